// Round 5
// baseline (732.676 us; speedup 1.0000x reference)
//
#include <hip/hip_runtime.h>
#include <hip/hip_bf16.h>

// ---------- types / helpers ----------
typedef __bf16 bf16x8 __attribute__((ext_vector_type(8)));
typedef float  f32x4  __attribute__((ext_vector_type(4)));
typedef unsigned int u32;
typedef u32 u32x4 __attribute__((ext_vector_type(4)));
typedef unsigned short ushort_t;

__device__ inline float bf2f(ushort_t h) {
    union { u32 u; float f; } v; v.u = ((u32)h) << 16; return v.f;
}
__device__ inline ushort_t f2bf(float f) {
    union { float f; u32 u; } v; v.f = f;
    u32 u = v.u;
    return (ushort_t)((u + 0x7fffu + ((u >> 16) & 1u)) >> 16);   // RNE
}
__device__ inline bf16x8 load_bf8(const ushort_t* p) {
    u32x4 u = *reinterpret_cast<const u32x4*>(p);
    return __builtin_bit_cast(bf16x8, u);
}
// dual-dtype loaders (idx in elements). f32flag=1 -> array is fp32.
__device__ inline bf16x8 load8_in(const void* base, size_t idx, int f32flag) {
    if (!f32flag) return load_bf8((const ushort_t*)base + idx);
    const float* pf = (const float*)base + idx;
    f32x4 a = *reinterpret_cast<const f32x4*>(pf);
    f32x4 b = *reinterpret_cast<const f32x4*>(pf + 4);
    bf16x8 r;
#pragma unroll
    for (int j = 0; j < 4; ++j) { r[j] = (__bf16)a[j]; r[4 + j] = (__bf16)b[j]; }
    return r;
}
__device__ inline float ld_in(const void* base, size_t idx, int f32flag) {
    return f32flag ? ((const float*)base)[idx] : bf2f(((const ushort_t*)base)[idx]);
}

// flags layout: [0]=q_emb [1]=s_emb [3]=W_lin [4]=b_lin [5]=W_out [6]=b_out [7]=ln_g [8]=ln_b
__device__ inline int f_of(const int* flags, int i) { return i < 0 ? 0 : flags[i]; }
__device__ inline int out_f32(const int* flags) {
    return flags[0] | flags[1] | flags[3] | flags[4] | flags[5] | flags[6] | flags[7] | flags[8];
}

// B=32, S=2048, D=256, split=128, hpd=4, dk=32, K=5, dilations (3,1). M=65536 rows.
#define PT_ROWS   80     // 64 block rows + 8 halo each side (need 6; 80 = 5 m-tiles)
#define PT_STRIDE 266    // ushorts/row = 133 words (odd) -> conflict-free LDS
#define XT_STRIDE 266

// ---------- kernel 0: dtype detector, one block per array ----------
__global__ __launch_bounds__(256) void detect8_kernel(
    const u32* p0, int n0, const u32* p1, int n1, const u32* p2, int n2, const u32* p3, int n3,
    const u32* p4, int n4, const u32* p5, int n5, const u32* p6, int n6, const u32* p7, int n7,
    int* __restrict__ flags)
{
    const u32* p; int n, slot;
    switch (blockIdx.x) {
        case 0: p = p0; n = n0; slot = 0; break;
        case 1: p = p1; n = n1; slot = 1; break;
        case 2: p = p2; n = n2; slot = 3; break;
        case 3: p = p3; n = n3; slot = 4; break;
        case 4: p = p4; n = n4; slot = 5; break;
        case 5: p = p5; n = n5; slot = 6; break;
        case 6: p = p6; n = n6; slot = 7; break;
        default: p = p7; n = n7; slot = 8; break;
    }
    const int t = threadIdx.x;
    int cn = 0, co = 0;
    for (int i = t; i < n; i += 256) {
        const u32 w = p[i];
        const u32 e  = (w >> 7) & 0xFF;
        const u32 fe = (w >> 23) & 0xFF;
        cn += (e >= 100 && e <= 135) ? 1 : 0;
        co += (((w & 0xFFFFu) == 0u) && fe >= 100 && fe <= 140) ? 1 : 0;
    }
    __shared__ int sn[256], so[256];
    sn[t] = cn; so[t] = co; __syncthreads();
    for (int o = 128; o; o >>= 1) {
        if (t < o) { sn[t] += sn[t + o]; so[t] += so[t + o]; }
        __syncthreads();
    }
    if (t == 0) {
        const int CN = sn[0], CO = so[0];
        flags[slot] = ((2 * CN < n) && ((2 * CO > n) || (20 * CN > n))) ? 1 : 0;
    }
}

// ---------- the per-stage mega kernel ----------
// STAGE 0 (A): P tile = proj(X=q_emb) in-LDS; attn (V=P); out-GEMM+res+LN -> hq to HA(SA)
//              and to LDS; then projC(hq, layer-2 W_lin) -> PC(SC).
// STAGE 1 (B): same from s_emb; probs -> d_out; hq(hs) NOT stored; projC(hs) -> PC(SB).
// STAGE 2 (C): P tile loaded from PRE(SC); V from VSRC(SB) global; out -> Z (out dtype).
template<int STAGE>
__global__ __launch_bounds__(256) void mega_kernel(
    const void* __restrict__ X, int xi,
    const ushort_t* __restrict__ PRE,
    const ushort_t* __restrict__ VSRC,
    const void* __restrict__ Wl,  size_t lwl,
    const void* __restrict__ bl,  size_t lbl,
    const void* __restrict__ WlC, size_t lwlC,
    const void* __restrict__ blC, size_t lblC,
    const void* __restrict__ Wo,  size_t lwo,
    const void* __restrict__ bo,  size_t lbo,
    const void* __restrict__ R,   int ri,
    const void* __restrict__ G, const void* __restrict__ Bt, size_t lg,
    ushort_t* __restrict__ HA,
    ushort_t* __restrict__ PC,
    void* __restrict__ Z,
    void* __restrict__ probs_base,
    const int* __restrict__ flags)
{
    __shared__ ushort_t Pt[PT_ROWS * PT_STRIDE];   // 42560 B
    __shared__ ushort_t xt[64 * XT_STRIDE];        // 34048 B
    __shared__ float lsum[4][64], lsq[4][64];      // 2048 B

    const int tid  = threadIdx.x;
    const int wave = tid >> 6, lane = tid & 63;
    const int l15  = lane & 15, quad = lane >> 4;
    const int m0   = blockIdx.x * 64;
    const int bb   = m0 >> 11;
    const int s0   = m0 & 2047;
    const size_t rowbase = (size_t)bb * 2048;
    const int og = out_f32(flags);

    // ---- phase 0: build P tile (batch rows s0-8 .. s0+71, clamped; halo>6 unused) ----
    if (STAGE < 2) {
        const int xf = f_of(flags, xi);
        const int wf = flags[3], bff = flags[4];
        const int dil = wave >> 1;
        const int no  = (wave & 1) * 64;
        bf16x8 bfr[4][4];   // [kc][nt] W_lin fragments, held in regs
#pragma unroll
        for (int kc = 0; kc < 4; ++kc)
#pragma unroll
            for (int nt = 0; nt < 4; ++nt)
                bfr[kc][nt] = load8_in(Wl, lwl + (size_t)dil * 16384 +
                    (size_t)(no + nt * 16 + l15) * 128 + kc * 32 + quad * 8, wf);
        float bias[4];
#pragma unroll
        for (int nt = 0; nt < 4; ++nt)
            bias[nt] = ld_in(bl, lbl + dil * 128 + no + nt * 16 + l15, bff);

#pragma unroll
        for (int mt = 0; mt < 5; ++mt) {
            int srow = s0 - 8 + mt * 16 + l15;
            srow = srow < 0 ? 0 : (srow > 2047 ? 2047 : srow);
            const size_t abase = (rowbase + srow) * 256 + dil * 128 + quad * 8;
            f32x4 acc[4] = {};
#pragma unroll
            for (int kc = 0; kc < 4; ++kc) {
                bf16x8 a = load8_in(X, abase + kc * 32, xf);
#pragma unroll
                for (int nt = 0; nt < 4; ++nt)
                    acc[nt] = __builtin_amdgcn_mfma_f32_16x16x32_bf16(a, bfr[kc][nt], acc[nt], 0, 0, 0);
            }
#pragma unroll
            for (int nt = 0; nt < 4; ++nt) {
                const int ncol = dil * 128 + no + nt * 16 + l15;
#pragma unroll
                for (int r = 0; r < 4; ++r)
                    Pt[(mt * 16 + quad * 4 + r) * PT_STRIDE + ncol] = f2bf(acc[nt][r] + bias[nt]);
            }
        }
    } else {
        // load pre-projected P tile from global
#pragma unroll
        for (int i = 0; i < 10; ++i) {
            const int chunk = tid + 256 * i;      // 2560 chunks of 8 ushorts
            const int trow = chunk >> 5, cc = chunk & 31;
            int srow = s0 - 8 + trow;
            srow = srow < 0 ? 0 : (srow > 2047 ? 2047 : srow);
            *reinterpret_cast<u32x4*>(&Pt[trow * PT_STRIDE + cc * 8]) =
                *reinterpret_cast<const u32x4*>(PRE + (rowbase + srow) * 256 + cc * 8);
        }
    }
    __syncthreads();

    // ---- phase 1: dilated attention (k/v from LDS; stage C v from global) ----
    const float scale = 0.17677669529663687f;   // 32^-0.5
#pragma unroll
    for (int it = 0; it < 2; ++it) {
        const int task = tid + 256 * it;
        const int r = task & 63, dg = task >> 6;
        const int dil = dg >> 2, g = dg & 3;
        const int dila = dil ? 1 : 3;            // DILATIONS = (3,1)
        const int s = s0 + r;
        const int ch = dil * 128 + g * 8;

        const ushort_t* qp = &Pt[(r + 8) * PT_STRIDE + ch];
        float qv[4][8];
#pragma unroll
        for (int h = 0; h < 4; ++h) {
            bf16x8 t = load_bf8(qp + h * 32);
#pragma unroll
            for (int j = 0; j < 8; ++j) qv[h][j] = (float)t[j];
        }
        float sc[5];
#pragma unroll
        for (int kk = 0; kk < 5; ++kk) {
            const int sp = s + (kk - 2) * dila;
            float a = 0.f;
            if (sp >= 0 && sp < 2048) {
                const ushort_t* kp = &Pt[(r + 8 + (kk - 2) * dila) * PT_STRIDE + ch];
#pragma unroll
                for (int h = 0; h < 4; ++h) {
                    bf16x8 t = load_bf8(kp + h * 32);
#pragma unroll
                    for (int j = 0; j < 8; ++j) a += qv[h][j] * (float)t[j];
                }
                a *= scale;
            }
            sc[kk] = a;
        }
        float mx = sc[0];
#pragma unroll
        for (int kk = 1; kk < 5; ++kk) mx = fmaxf(mx, sc[kk]);
        float p[5], sum = 0.f;
#pragma unroll
        for (int kk = 0; kk < 5; ++kk) { p[kk] = __expf(sc[kk] - mx); sum += p[kk]; }
        const float inv = 1.f / sum;
#pragma unroll
        for (int kk = 0; kk < 5; ++kk) p[kk] *= inv;

        float o[4][8] = {};
#pragma unroll
        for (int kk = 0; kk < 5; ++kk) {
            const int sp = s + (kk - 2) * dila;
            if (sp < 0 || sp >= 2048) continue;
            const ushort_t* vp = (STAGE < 2)
                ? &Pt[(r + 8 + (kk - 2) * dila) * PT_STRIDE + ch]
                : (VSRC + (rowbase + sp) * 256 + ch);
#pragma unroll
            for (int h = 0; h < 4; ++h) {
                bf16x8 t = load_bf8(vp + h * 32);
#pragma unroll
                for (int j = 0; j < 8; ++j) o[h][j] += p[kk] * (float)t[j];
            }
        }
        // pack attn result (channel dil*128+g*32+d2, value o[d2&3][d2>>2]) into xt
        ushort_t* op = &xt[r * XT_STRIDE + dil * 128 + g * 32];
#pragma unroll
        for (int c = 0; c < 4; ++c) {
            u32x4 w;
#pragma unroll
            for (int t4 = 0; t4 < 4; ++t4) {
                const int d2a = c * 8 + t4 * 2, d2b = d2a + 1;
                const u32 lo = f2bf(o[d2a & 3][d2a >> 2]);
                const u32 hi = f2bf(o[d2b & 3][d2b >> 2]);
                w[t4] = lo | (hi << 16);
            }
            *reinterpret_cast<u32x4*>(op + c * 8) = w;
        }
        if (STAGE == 1) {
            const size_t pb = 16777216 + ((size_t)((bb * 8 + dg) * 2048 + s)) * 5;
            if (og) {
                float* pp = (float*)probs_base;
#pragma unroll
                for (int kk = 0; kk < 5; ++kk) pp[pb + kk] = p[kk];
            } else {
                ushort_t* pp = (ushort_t*)probs_base;
#pragma unroll
                for (int kk = 0; kk < 5; ++kk) pp[pb + kk] = f2bf(p[kk]);
            }
        }
    }
    __syncthreads();

    // ---- phase 2: out-GEMM + bias + residual + LN ----
    const int wf2 = flags[5], bvf = flags[6], gf = flags[7], btf = flags[8];
    const int rf = f_of(flags, ri);
    const int n_off = wave * 64;

    f32x4 acc[4][4] = {};
    for (int kc = 0; kc < 8; ++kc) {
        bf16x8 a[4], b[4];
#pragma unroll
        for (int mt = 0; mt < 4; ++mt)
            a[mt] = load_bf8(&xt[(mt * 16 + l15) * XT_STRIDE + kc * 32 + quad * 8]);
#pragma unroll
        for (int nt = 0; nt < 4; ++nt)
            b[nt] = load8_in(Wo, lwo + (size_t)(n_off + nt * 16 + l15) * 256 + kc * 32 + quad * 8, wf2);
#pragma unroll
        for (int mt = 0; mt < 4; ++mt)
#pragma unroll
            for (int nt = 0; nt < 4; ++nt)
                acc[mt][nt] = __builtin_amdgcn_mfma_f32_16x16x32_bf16(a[mt], b[nt], acc[mt][nt], 0, 0, 0);
    }

    float bias[4];
#pragma unroll
    for (int nt = 0; nt < 4; ++nt) bias[nt] = ld_in(bo, lbo + n_off + nt * 16 + l15, bvf);

    float psum[4][4] = {}, psq[4][4] = {};
#pragma unroll
    for (int mt = 0; mt < 4; ++mt) {
#pragma unroll
        for (int rr = 0; rr < 4; ++rr) {
            const size_t rrow = (size_t)(m0 + mt * 16 + quad * 4 + rr) * 256 + l15;
#pragma unroll
            for (int nt = 0; nt < 4; ++nt) {
                float v = acc[mt][nt][rr] + bias[nt] + ld_in(R, rrow + n_off + nt * 16, rf);
                acc[mt][nt][rr] = v;
                psum[mt][rr] += v;
                psq[mt][rr]  += v * v;
            }
        }
    }
#pragma unroll
    for (int off = 1; off <= 8; off <<= 1) {
#pragma unroll
        for (int mt = 0; mt < 4; ++mt)
#pragma unroll
            for (int rr = 0; rr < 4; ++rr) {
                psum[mt][rr] += __shfl_xor(psum[mt][rr], off);
                psq[mt][rr]  += __shfl_xor(psq[mt][rr],  off);
            }
    }
    if (l15 == 0) {
#pragma unroll
        for (int mt = 0; mt < 4; ++mt)
#pragma unroll
            for (int rr = 0; rr < 4; ++rr) {
                const int row = mt * 16 + quad * 4 + rr;
                lsum[wave][row] = psum[mt][rr];
                lsq[wave][row]  = psq[mt][rr];
            }
    }
    __syncthreads();   // also guarantees all waves finished reading xt in the kc loop

    float gl[4], blv[4];
#pragma unroll
    for (int nt = 0; nt < 4; ++nt) {
        gl[nt]  = ld_in(G,  lg + n_off + nt * 16 + l15, gf);
        blv[nt] = ld_in(Bt, lg + n_off + nt * 16 + l15, btf);
    }
#pragma unroll
    for (int mt = 0; mt < 4; ++mt) {
#pragma unroll
        for (int rr = 0; rr < 4; ++rr) {
            const int row = mt * 16 + quad * 4 + rr;
            const float sm = lsum[0][row] + lsum[1][row] + lsum[2][row] + lsum[3][row];
            const float q2 = lsq[0][row]  + lsq[1][row]  + lsq[2][row]  + lsq[3][row];
            const float mu  = sm * (1.f / 256.f);
            const float var = q2 * (1.f / 256.f) - mu * mu;
            const float rs  = rsqrtf(var + 1e-5f);
#pragma unroll
            for (int nt = 0; nt < 4; ++nt) {
                const int col = n_off + nt * 16 + l15;
                const float hv = (acc[mt][nt][rr] - mu) * rs * gl[nt] + blv[nt];
                if (STAGE == 0) {
                    HA[(size_t)(m0 + row) * 256 + col] = f2bf(hv);
                    xt[row * XT_STRIDE + col] = f2bf(hv);
                } else if (STAGE == 1) {
                    xt[row * XT_STRIDE + col] = f2bf(hv);
                } else {
                    const size_t zi = (size_t)(m0 + row) * 256 + col;
                    if (og) ((float*)Z)[zi] = hv;
                    else    ((ushort_t*)Z)[zi] = f2bf(hv);
                }
            }
        }
    }

    // ---- phase 3 (A/B): layer-2 projection of the LN result -> PC (global bf16) ----
    if (STAGE < 2) {
        __syncthreads();
        const int wf = flags[3], bff = flags[4];
        const int dil = wave >> 1;
        const int no  = (wave & 1) * 64;
        bf16x8 bfr[4][4];
#pragma unroll
        for (int kc = 0; kc < 4; ++kc)
#pragma unroll
            for (int nt = 0; nt < 4; ++nt)
                bfr[kc][nt] = load8_in(WlC, lwlC + (size_t)dil * 16384 +
                    (size_t)(no + nt * 16 + l15) * 128 + kc * 32 + quad * 8, wf);
        float bias2[4];
#pragma unroll
        for (int nt = 0; nt < 4; ++nt)
            bias2[nt] = ld_in(blC, lblC + dil * 128 + no + nt * 16 + l15, bff);
#pragma unroll
        for (int mt = 0; mt < 4; ++mt) {
            f32x4 acc2[4] = {};
#pragma unroll
            for (int kc = 0; kc < 4; ++kc) {
                bf16x8 a = load_bf8(&xt[(mt * 16 + l15) * XT_STRIDE + dil * 128 + kc * 32 + quad * 8]);
#pragma unroll
                for (int nt = 0; nt < 4; ++nt)
                    acc2[nt] = __builtin_amdgcn_mfma_f32_16x16x32_bf16(a, bfr[kc][nt], acc2[nt], 0, 0, 0);
            }
#pragma unroll
            for (int nt = 0; nt < 4; ++nt) {
                const int ncol = dil * 128 + no + nt * 16 + l15;
#pragma unroll
                for (int r = 0; r < 4; ++r)
                    PC[(size_t)(m0 + mt * 16 + quad * 4 + r) * 256 + ncol] = f2bf(acc2[nt][r] + bias2[nt]);
            }
        }
    }
}

// ---------- launch ----------
extern "C" void kernel_launch(void* const* d_in, const int* in_sizes, int n_in,
                              void* d_out, int out_size, void* d_ws, size_t ws_size,
                              hipStream_t stream) {
    const void* q_emb = d_in[0];
    const void* s_emb = d_in[1];
    const void* W_lin = d_in[3];   // (3,2,128,128) layer stride 32768 elems
    const void* b_lin = d_in[4];   // (3,2,128)     layer stride 256
    const void* W_out = d_in[5];   // (3,256,256)   layer stride 65536
    const void* b_out = d_in[6];   // (3,256)       layer stride 256
    const void* ln_g  = d_in[7];
    const void* ln_b  = d_in[8];

    const size_t SLOT = 16777216;
    int*      flags = (int*)d_ws;
    ushort_t* SA = (ushort_t*)((char*)d_ws + 256);   // hq (bf16)
    ushort_t* SB = SA + SLOT;                        // VC = proj(hs, layer2) (bf16)
    ushort_t* SC = SA + 2 * SLOT;                    // PC = proj(hq, layer2) (bf16)
    // d_ws footprint: 256 B + 3 x 33.55 MB = 100.7 MB (proven resident)

    detect8_kernel<<<8, 256, 0, stream>>>(
        (const u32*)q_emb, 16384, (const u32*)s_emb, 16384,
        (const u32*)W_lin, 16384, (const u32*)b_lin, 384,
        (const u32*)W_out, 16384, (const u32*)b_out, 384,
        (const u32*)ln_g, 384, (const u32*)ln_b, 384, flags);

    // ---- stage A: hq = LN(q_emb + mha(q_emb)) -> SA ; PC = proj(hq, L2) -> SC
    mega_kernel<0><<<1024, 256, 0, stream>>>(
        q_emb, 0, nullptr, nullptr,
        W_lin, 0, b_lin, 0,
        W_lin, 65536, b_lin, 512,
        W_out, 0, b_out, 0,
        q_emb, 0,
        ln_g, ln_b, 0,
        SA, SC, nullptr, nullptr, flags);
    // ---- stage B: hs = LN(s_emb + mha(s_emb)) (not stored); probs -> d_out; VC = proj(hs, L2) -> SB
    mega_kernel<1><<<1024, 256, 0, stream>>>(
        s_emb, 1, nullptr, nullptr,
        W_lin, 32768, b_lin, 256,
        W_lin, 65536, b_lin, 512,
        W_out, 65536, b_out, 256,
        s_emb, 1,
        ln_g, ln_b, 256,
        nullptr, SB, nullptr, d_out, flags);
    // ---- stage C: z = LN(hq + attn(PC, PC, VC) @ Wo + bo) -> d_out
    mega_kernel<2><<<1024, 256, 0, stream>>>(
        nullptr, -1, SC, SB,
        nullptr, 0, nullptr, 0,
        nullptr, 0, nullptr, 0,
        W_out, 131072, b_out, 512,
        SA, -1,
        ln_g, ln_b, 512,
        nullptr, nullptr, d_out, nullptr, flags);
}